// Round 3
// baseline (193.618 us; speedup 1.0000x reference)
//
#include <hip/hip_runtime.h>

// R7 == R6 resubmitted byte-identical (R6 bench was an infra failure:
// "MI355X container failed twice" — no compile/correctness verdict).

#define NPTS  64
#define NANG  2016          // 64*63/2
#define NCOLS 300000
#define NC4   (NCOLS / 4)   // 75000 float4 columns

typedef float v4 __attribute__((ext_vector_type(4)));

#define PSTR 68             // LDS row stride in floats: 16B-aligned (68*4=272=17*16)
                            // and bank-offset 4 -> row-adjacent scalar reads conflict-free

// ---------------------------------------------------------------------------
// Kernel 1: build A^T (mus folded) into d_ws as AT[k*64 + row] = mus[row]*R[row][k].
//
// R6: R5 measured ~47us = ~44cyc/rotation -- ONE wave executing a 2016-deep
// serial chain (sincos + readlane stream + fma chain on a single SIMD, no TLP).
// Fix: segment the chain. R = M3 @ M2 @ M1 @ M0 where Mw = product of groups
// t in [Tw, Tw+1). A segment starting at t0 is identity on rows/cols < t0,
// dense on [t0..63]^2. Boundaries {0,9,19,32,63} balance real rotations
// (531/495/494/496) across the 4 waves of one 256-thread block (1 wave/SIMD).
// Per wave: precompute ALL (c,s) into registers (independent sincosf, latency
// hidden), then run the shift-register with EXACT group lengths (no identity
// padding), (c,s) broadcast by imm-lane v_readlane (register file, no memory).
// Combine: three block-wide LDS matmuls, rows >= t0 only, k-range from
// floor(t0/4) (cols < t0 of Mw are exact zeros by construction). v4 row reads
// are wave-broadcast (conflict-free); slabs padded to PSTR=68.
// ---------------------------------------------------------------------------

__device__ __forceinline__ float rl(float x, int lane) {
    return __uint_as_float(__builtin_amdgcn_readlane(__float_as_uint(x), lane));
}

// Groups T..TB-1, exact length 63-T each. S[j] = running[row T+j][col lane].
// Rotation i (1-based) of group T: rows (T, T+i); lane i-1 holds its (c,s).
template<int T, int TB, int TA, int NG>
__device__ __forceinline__ void groups_run(float (&S)[NPTS],
                                           const float (&c)[NG], const float (&s)[NG],
                                           float* __restrict__ slab, int lane)
{
    if constexpr (T < TB) {
        constexpr int g   = T - TA;
        constexpr int LEN = 63 - T;                   // real rotations in group T
        float rt = S[0];
        #pragma unroll
        for (int i = 1; i <= LEN; ++i) {              // compile-time i
            const float cc = rl(c[g], i - 1);         // v_readlane, imm lane
            const float ss = rl(s[g], i - 1);
            const float rb = S[i];
            S[i - 1] = fmaf(ss, rt, cc * rb);         // new row (T+i), pre-shifted
            rt       = fmaf(cc, rt, -ss * rb);        // serial chain
        }
        slab[T * PSTR + lane] = rt;                   // row T of Mw finished
        groups_run<T + 1, TB, TA, NG>(S, c, s, slab, lane);
    }
}

template<int TA, int TB>
__device__ __forceinline__ void do_wave(const float* __restrict__ angles,
                                        float* __restrict__ slab, int lane)
{
    constexpr int NG = TB - TA;
    float c[NG], s[NG];
    #pragma unroll
    for (int g = 0; g < NG; ++g) {                    // all independent -> pipelined
        const int t    = TA + g;
        const int base = 63 * t - (t * (t - 1)) / 2;  // angle base of group t
        float a = 0.0f;
        if (lane < 63 - t) a = angles[base + lane];   // lane i-1 <-> rotation i
        sincosf(a, &s[g], &c[g]);
    }

    // segment starts from identity restricted to rows TA..TA+63 (cols<TA: all 0)
    float S[NPTS];
    #pragma unroll
    for (int j = 0; j < NPTS; ++j) S[j] = (TA + j == lane) ? 1.0f : 0.0f;

    groups_run<TA, TB, TA, NG>(S, c, s, slab, lane);

    // rows TB..63 of Mw still live in S[0..63-TB]
    #pragma unroll
    for (int j = 0; j <= 63 - TB; ++j)
        slab[(TB + j) * PSTR + lane] = S[j];
}

// P[rows >= RS] = Ms[RS: , RS:] @ P[RS: , :]; rows < RS of P unchanged.
// k4 starts at RS/4: Ms cols < RS are exact zeros, so partial quads are safe.
template<int RS>
__device__ __forceinline__ void combine_step(float* __restrict__ P,
                                             const float* __restrict__ Ms,
                                             int tid)
{
    const int c4 = tid & 15;                          // v4 column 0..15
    const int rg = tid >> 4;                          // row group 0..15
    constexpr int NR   = 64 - RS;
    constexpr int NIT  = (NR + 15) / 16;
    constexpr int K4_0 = RS / 4;

    v4 acc[NIT];
    #pragma unroll
    for (int it = 0; it < NIT; ++it) acc[it] = (v4)0.0f;

    #pragma unroll 2
    for (int k4 = K4_0; k4 < 16; ++k4) {
        v4 pv[4];
        #pragma unroll
        for (int j = 0; j < 4; ++j)                   // same addr across lanes-of-16:
            pv[j] = *(const v4*)(P + (4 * k4 + j) * PSTR + 4 * c4);   // broadcast
        #pragma unroll
        for (int it = 0; it < NIT; ++it) {
            const int r = RS + rg + 16 * it;
            if (r < 64) {
                const v4 mv = *(const v4*)(Ms + r * PSTR + 4 * k4);
                acc[it] += pv[0] * mv.x;
                acc[it] += pv[1] * mv.y;
                acc[it] += pv[2] * mv.z;
                acc[it] += pv[3] * mv.w;
            }
        }
    }
    __syncthreads();                                  // all reads of P done
    #pragma unroll
    for (int it = 0; it < NIT; ++it) {
        const int r = RS + rg + 16 * it;
        if (r < 64) *(v4*)(P + r * PSTR + 4 * c4) = acc[it];
    }
    __syncthreads();
}

__global__ __launch_bounds__(256, 1) void ortho_build_R(
    const float* __restrict__ angles, const float* __restrict__ mus,
    float* __restrict__ AT_out)
{
    __shared__ float P[NPTS * PSTR];                  // M0, then running product
    __shared__ float M[3][NPTS * PSTR];               // M1, M2, M3 slabs

    const int tid  = threadIdx.x;
    const int lane = tid & 63;
    const int wv   = tid >> 6;

    if      (wv == 0) do_wave< 0,  9>(angles, P,    lane);   // 531 rotations
    else if (wv == 1) do_wave< 9, 19>(angles, M[0], lane);   // 495
    else if (wv == 2) do_wave<19, 32>(angles, M[1], lane);   // 494
    else              do_wave<32, 63>(angles, M[2], lane);   // 496
    __syncthreads();

    combine_step< 9>(P, M[0], tid);                   // P <- M1 @ P (rows 9..63)
    combine_step<19>(P, M[1], tid);                   // P <- M2 @ P (rows 19..63)
    combine_step<32>(P, M[2], tid);                   // P <- M3 @ P (rows 32..63)

    // AT[k*64 + r] = mus[r] * R[r][k]; lane = r -> coalesced 256B global stores,
    // P column read is a 16-instr LDS blip (stride-68 = 8-way, negligible).
    #pragma unroll
    for (int i = 0; i < 16; ++i) {
        const int idx = i * 256 + tid;                // 0..4095
        const int r   = idx & 63;
        const int k   = idx >> 6;
        AT_out[k * NPTS + r] = mus[r] * P[r * PSTR + k];
    }
}

// ---------------------------------------------------------------------------
// Kernel 2: Y = A @ X (unchanged — byte-identical to keep the build_R delta
// attribution clean). Thread tile = 16 rows x 4 cols; A reads wave-uniform-
// address global loads; X coalesced float4, double-buffered.
// ---------------------------------------------------------------------------
__device__ __forceinline__ void step16(v4 (&acc)[16], const float* __restrict__ Ak,
                                       const v4 xv)
{
    #pragma unroll
    for (int q = 0; q < 4; ++q) {
        const v4 a = *(const v4*)(Ak + 4 * q);
        acc[4 * q + 0] += xv * a.x;
        acc[4 * q + 1] += xv * a.y;
        acc[4 * q + 2] += xv * a.z;
        acc[4 * q + 3] += xv * a.w;
    }
}

__global__ __launch_bounds__(256) void ortho_apply(
    const float* __restrict__ X, const float* __restrict__ AT,
    float* __restrict__ Y)
{
    const int tc = threadIdx.x & 63;
    const int wv = threadIdx.x >> 6;
    const int tr = __builtin_amdgcn_readfirstlane(wv);   // wave-uniform 0..3
    const int r0 = tr * 16;

    const int j4 = blockIdx.x * 64 + tc;                 // float4 column index
    if (j4 >= NC4) return;

    const v4* xp = (const v4*)X + j4;                    // row stride NC4

    v4 acc[16];
    #pragma unroll
    for (int i = 0; i < 16; ++i) acc[i] = (v4)0.0f;

    v4 xa[4], xb[4];
    #pragma unroll
    for (int q = 0; q < 4; ++q) xa[q] = xp[q * NC4];

    for (int k0 = 0; k0 < NPTS; k0 += 8) {
        #pragma unroll
        for (int q = 0; q < 4; ++q) xb[q] = xp[(k0 + 4 + q) * NC4];
        #pragma unroll
        for (int q = 0; q < 4; ++q) step16(acc, AT + (k0 + q) * NPTS + r0, xa[q]);
        #pragma unroll
        for (int q = 0; q < 4; ++q) xa[q] = xp[((k0 + 8 + q) & 63) * NC4]; // wraps last iter (harmless)
        #pragma unroll
        for (int q = 0; q < 4; ++q) step16(acc, AT + (k0 + 4 + q) * NPTS + r0, xb[q]);
    }

    #pragma unroll
    for (int i = 0; i < 16; ++i) {
        v4* yp = (v4*)(Y + (size_t)(r0 + i) * NCOLS) + j4;
        __builtin_nontemporal_store(acc[i], yp);
    }
}

// ---------------------------------------------------------------------------
extern "C" void kernel_launch(void* const* d_in, const int* in_sizes, int n_in,
                              void* d_out, int out_size, void* d_ws, size_t ws_size,
                              hipStream_t stream) {
    const float* X      = (const float*)d_in[0];   // 64 x 300000
    const float* angles = (const float*)d_in[1];   // 2016
    const float* mus    = (const float*)d_in[2];   // 64
    float* Y  = (float*)d_out;                     // 64 x 300000
    float* AT = (float*)d_ws;                      // 64 x 64 scratch

    ortho_build_R<<<1, 256, 0, stream>>>(angles, mus, AT);

    const int nblk = (NC4 + 63) / 64;              // 1172
    ortho_apply<<<nblk, 256, 0, stream>>>(X, AT, Y);
}